// Round 11
// baseline (268.645 us; speedup 1.0000x reference)
//
#include <hip/hip_runtime.h>
#include <math.h>

#define BB 512
#define SS 200
#define DDIM 64
#define HD 32
#define LL 2
#define NROWS (BB * SS)   // 102400
#define EPS 1e-8f
#define CC 0.001f
#define GRAM_NB 256       // blocks PER INPUT; combined kernel launches 2*GRAM_NB
#define LSTRIDE 72
#define XS 68             // Xf f32 LDS stride
#define QROWS 208         // Qb/Kb rows (16-row tiles up to 207 for tile 12)

typedef __attribute__((ext_vector_type(8))) short bf16x8;
typedef __attribute__((ext_vector_type(4))) float f32x4;

// ---------------- static device buffers ----------------
__device__ unsigned short g_qb[NROWS * DDIM];   // final bf16 x (gram-FF input)
__device__ float g_gpart[2 * GRAM_NB * 4096];   // gram per-block partials (EE slabs then FF slabs)
// pre-converted bf16 weights: qkv(2x12288)@0, out(2x4096)@24576, fc1@32768, fc2@40960
__device__ unsigned short g_wb[49152];

// ---------------- helpers ----------------
__device__ __forceinline__ float wave_sum(float v) {
#pragma unroll
    for (int o = 32; o > 0; o >>= 1) v += __shfl_xor(v, o, 64);
    return v;
}
__device__ __forceinline__ unsigned short f2b(float f) {
    unsigned u = __float_as_uint(f);
    return (unsigned short)((u + 0x7FFFu + ((u >> 16) & 1u)) >> 16);
}

// ---------------- one-time weight f32 -> bf16 conversion ----------------
__global__ __launch_bounds__(256) void prep_weights(const float* __restrict__ qkv_w,
                                                    const float* __restrict__ out_w,
                                                    const float* __restrict__ fc1_w,
                                                    const float* __restrict__ fc2_w,
                                                    unsigned short* __restrict__ wb) {
    int i4 = (blockIdx.x * 256 + threadIdx.x) * 4;   // grid 48 blocks covers 49152
    const float* src; int off;
    if (i4 < 24576)      { src = qkv_w; off = 0; }
    else if (i4 < 32768) { src = out_w; off = 24576; }
    else if (i4 < 40960) { src = fc1_w; off = 32768; }
    else                 { src = fc2_w; off = 40960; }
    float4 f = *(const float4*)&src[i4 - off];
    ushort4 o; o.x = f2b(f.x); o.y = f2b(f.y); o.z = f2b(f.z); o.w = f2b(f.w);
    *(ushort4*)&wb[i4] = o;
}

// ---------------- fragment builders (from LDS f32 x + per-row LN stats) ----------------
__device__ __forceinline__ bf16x8 frag_raw(const float* Xf, int row, int c0) {
    const float* p = &Xf[row * XS + c0];
    float4 u = *(const float4*)p;
    float4 v = *(const float4*)(p + 4);
    bf16x8 r;
    r[0] = (short)f2b(u.x); r[1] = (short)f2b(u.y); r[2] = (short)f2b(u.z); r[3] = (short)f2b(u.w);
    r[4] = (short)f2b(v.x); r[5] = (short)f2b(v.y); r[6] = (short)f2b(v.z); r[7] = (short)f2b(v.w);
    return r;
}
__device__ __forceinline__ bf16x8 frag_ln(const float* Xf, const float* stats,
                                          const float* vw, const float* vb,
                                          int row, int c0) {
    float m = stats[row * 2], rs = stats[row * 2 + 1];
    const float* p = &Xf[row * XS + c0];
    float4 u = *(const float4*)p;
    float4 v = *(const float4*)(p + 4);
    bf16x8 r;
    r[0] = (short)f2b((u.x - m) * rs * vw[c0 + 0] + vb[c0 + 0]);
    r[1] = (short)f2b((u.y - m) * rs * vw[c0 + 1] + vb[c0 + 1]);
    r[2] = (short)f2b((u.z - m) * rs * vw[c0 + 2] + vb[c0 + 2]);
    r[3] = (short)f2b((u.w - m) * rs * vw[c0 + 3] + vb[c0 + 3]);
    r[4] = (short)f2b((v.x - m) * rs * vw[c0 + 4] + vb[c0 + 4]);
    r[5] = (short)f2b((v.y - m) * rs * vw[c0 + 5] + vb[c0 + 5]);
    r[6] = (short)f2b((v.z - m) * rs * vw[c0 + 6] + vb[c0 + 6]);
    r[7] = (short)f2b((v.w - m) * rs * vw[c0 + 7] + vb[c0 + 7]);
    return r;
}

// one 16-col output tile: B-fragment straight from L2-hot bf16 global weights
__device__ __forceinline__ f32x4 gemm1(bf16x8 a0, bf16x8 a1,
                                       const unsigned short* __restrict__ Wg,
                                       int nt, int m16, int quad) {
    bf16x8 b0 = *(const bf16x8*)&Wg[(nt * 16 + m16) * 64 + quad * 8];
    bf16x8 b1 = *(const bf16x8*)&Wg[(nt * 16 + m16) * 64 + 32 + quad * 8];
    f32x4 acc = {0.f, 0.f, 0.f, 0.f};
    acc = __builtin_amdgcn_mfma_f32_16x16x32_bf16(a0, b0, acc, 0, 0, 0);
    acc = __builtin_amdgcn_mfma_f32_16x16x32_bf16(a1, b1, acc, 0, 0, 0);
    return acc;
}

// ---------------- mega kernel: one block per batch element, 16 waves ----------------
// r10 post-mortem: spills eliminated (WRITE 12.8MB = xb only) but time unchanged ->
// barrier-bound. This version removes the shared LDS weight tile: B-fragments read
// per-nt from L2-hot bf16 weights, QKV is one phase, FFN has zero block barriers
// (all wave-local). 4 __syncthreads per layer instead of ~12.
__global__ __launch_bounds__(1024)
void mega(const int* __restrict__ log_seqs,
          const int* __restrict__ pos_seqs,
          const float* __restrict__ item_emb,
          const float* __restrict__ pos_emb,
          const float* __restrict__ pred_w,
          const float* __restrict__ ln_w,  const float* __restrict__ ln_b,
          const float* __restrict__ qkv_b,
          const float* __restrict__ out_b,
          const float* __restrict__ fc1_b, const float* __restrict__ fc2_b,
          const float* __restrict__ ffln_w, const float* __restrict__ ffln_b,
          const float* __restrict__ ffln2_w, const float* __restrict__ ffln2_b,
          const unsigned short* __restrict__ wb,
          unsigned short* __restrict__ xb,
          float* __restrict__ rpart,
          unsigned int* __restrict__ cnt) {
    __shared__ float Xf[200 * XS];               // 54,400 B  f32 activations / x1 stash
    __shared__ unsigned short Qb[QROWS * 72];    // 29,952 B  q -> P scratch -> ctx
    __shared__ unsigned short Kb[QROWS * 72];    // 29,952 B  k -> FFN scratch
    __shared__ unsigned short Vt[64 * 232];      // 29,696 B  V transposed [d][kk], pad cols 200..231 zero
    __shared__ float stats[200 * 2];             // 1,600 B   per-row (mean, rs)
    __shared__ float vecs[13][64];               // 3,328 B
    __shared__ float redw[16];
    // total 148,992 B -> 1 block/CU, 16 waves

    const int t = threadIdx.x, b = blockIdx.x;
    const int w = t >> 6, lane = t & 63, m16 = lane & 15, quad = lane >> 4;
    const f32x4 Z = {0.f, 0.f, 0.f, 0.f};

    if (b == 0 && t == 0) *cnt = 0u;             // reset reduce_final's done-counter
    if (t < 64) vecs[12][t] = pred_w[t];
    // Vt zero-pad cols 200..231, once (V writes are guarded to cols <200)
    if (t < 512) {
        int r2 = t >> 3, cc = 200 + (t & 7) * 4;
        ushort4 z4; z4.x = z4.y = z4.z = z4.w = 0;
        *(ushort4*)&Vt[r2 * 232 + cc] = z4;
    }
    // ---- embed + layer-0 LN stats (4 lanes per row; wave w owns rows 16w..16w+15) ----
    {
        int rr = t >> 2;
        if (rr < 200) {
            int li = log_seqs[b * SS + rr];
            int poss = li ? (rr + 1) : 0;
            int qd = (t & 3) * 16;
            float4 v[4];
#pragma unroll
            for (int g = 0; g < 4; ++g) {
                float4 e = *(const float4*)&item_emb[(long)li * DDIM + qd + g * 4];
                float4 p = *(const float4*)&pos_emb[(long)poss * DDIM + qd + g * 4];
                v[g].x = e.x * 8.0f + p.x; v[g].y = e.y * 8.0f + p.y;
                v[g].z = e.z * 8.0f + p.z; v[g].w = e.w * 8.0f + p.w;
                *(float4*)&Xf[rr * XS + qd + g * 4] = v[g];
            }
            float s1 = 0.f, s2 = 0.f;
#pragma unroll
            for (int g = 0; g < 4; ++g) {
                s1 += (v[g].x + v[g].y) + (v[g].z + v[g].w);
                s2 += (v[g].x * v[g].x + v[g].y * v[g].y) + (v[g].z * v[g].z + v[g].w * v[g].w);
            }
            s1 += __shfl_xor(s1, 1, 64); s1 += __shfl_xor(s1, 2, 64);
            s2 += __shfl_xor(s2, 1, 64); s2 += __shfl_xor(s2, 2, 64);
            float mean = s1 * (1.f / 64.f);
            float var = s2 * (1.f / 64.f) - mean * mean;
            float rs = rsqrtf(var + EPS);
            if ((t & 3) == 0) { stats[rr * 2] = mean; stats[rr * 2 + 1] = rs; }
        }
    }

    for (int l = 0; l < LL; ++l) {
        __syncthreads();                 // prev phase (embed / FFN) complete
        if (t < 64) {
            vecs[0][t] = qkv_b[l * 192 + t];
            vecs[1][t] = qkv_b[l * 192 + 64 + t];
            vecs[2][t] = qkv_b[l * 192 + 128 + t];
            vecs[3][t] = ln_w[l * 64 + t];   vecs[4][t] = ln_b[l * 64 + t];
            vecs[5][t] = out_b[l * 64 + t];
            vecs[6][t] = fc1_b[l * 64 + t];  vecs[7][t] = fc2_b[l * 64 + t];
            vecs[8][t] = ffln_w[l * 64 + t]; vecs[9][t] = ffln_b[l * 64 + t];
            vecs[10][t] = ffln2_w[l * 64 + t]; vecs[11][t] = ffln2_b[l * 64 + t];
        }
        __syncthreads();
        // ---- QKV phase (single): wave w owns 16-row tile; B from global bf16 ----
        if (w < 13) {
            const unsigned short* wq = wb + l * 12288;
            int tb = w * 16;
            int row = tb + m16; if (row > 199) row = 199;
            // Q (A = LN(x))
            {
                bf16x8 a0 = frag_ln(Xf, stats, vecs[3], vecs[4], row, quad * 8);
                bf16x8 a1 = frag_ln(Xf, stats, vecs[3], vecs[4], row, 32 + quad * 8);
#pragma unroll
                for (int nt = 0; nt < 4; ++nt) {
                    f32x4 acc = gemm1(a0, a1, wq, nt, m16, quad);
                    int n = nt * 16 + m16; float bbv = vecs[0][n];
#pragma unroll
                    for (int rg = 0; rg < 4; ++rg)
                        Qb[(tb + quad * 4 + rg) * 72 + n] = f2b(acc[rg] + bbv);
                }
            }
            // K + V (A = bf16(x), computed once)
            {
                bf16x8 a0 = frag_raw(Xf, row, quad * 8);
                bf16x8 a1 = frag_raw(Xf, row, 32 + quad * 8);
#pragma unroll
                for (int nt = 0; nt < 4; ++nt) {
                    f32x4 acc = gemm1(a0, a1, wq + 4096, nt, m16, quad);
                    int n = nt * 16 + m16; float bbv = vecs[1][n];
#pragma unroll
                    for (int rg = 0; rg < 4; ++rg)
                        Kb[(tb + quad * 4 + rg) * 72 + n] = f2b(acc[rg] + bbv);
                }
#pragma unroll
                for (int nt = 0; nt < 4; ++nt) {
                    f32x4 acc = gemm1(a0, a1, wq + 8192, nt, m16, quad);
                    int n = nt * 16 + m16; float bbv = vecs[2][n];
#pragma unroll
                    for (int rg = 0; rg < 4; ++rg) {
                        int m = tb + quad * 4 + rg;
                        if (m < 200) Vt[n * 232 + m] = f2b(acc[rg] + bbv);   // keep pad zero
                    }
                }
            }
        }
        __syncthreads();
        // ---- attention: 26 (h,qt) units over waves 0..13, np<=7 each; P reuses own Q region ----
        {
            const unsigned long long tab0 = 0x01170016FF19FF18ull;
            const unsigned long long tab1 = 0x0513041203150214ull;
            const unsigned long long tab2 = 0x090F080E07110610ull;
            const unsigned long long tab3 = 0xFFFFFFFF0B0D0A0Cull;
            unsigned long long tv = (w & 8) ? ((w & 4) ? tab3 : tab2) : ((w & 4) ? tab1 : tab0);
            unsigned su = (unsigned)((tv >> ((w & 3) * 16)) & 0xFFFFu);
            const float scale = 0.17677669529663687f;   // 1/sqrt(32)
            for (int slot = 0; slot < 2; ++slot) {
                int u = (su >> (slot * 8)) & 0xFF;
                if (u == 0xFF) break;
                int h = u & 1, qt = u >> 1;
                int q0 = qt * 16;
                int qrow = q0 + m16; if (qrow > 199) qrow = 199;
                bf16x8 qa = *(const bf16x8*)&Qb[qrow * 72 + h * 32 + quad * 8];
                __builtin_amdgcn_wave_barrier();
                unsigned short* ps = &Qb[q0 * 72 + h * 32];   // this unit's (now dead) Q region
                f32x4 o0 = Z, o1 = Z;
                float lsum[4] = {0.f, 0.f, 0.f, 0.f};
                int np = (qt + 2) >> 1;
                for (int pi = 0; pi < np; ++pi) {
                    int p0 = pi * 32;
                    int kr0 = p0 + m16;      int kr0c = kr0 > 199 ? 199 : kr0;
                    int kr1 = p0 + 16 + m16; int kr1c = kr1 > 199 ? 199 : kr1;
                    bf16x8 kb0 = *(const bf16x8*)&Kb[kr0c * 72 + h * 32 + quad * 8];
                    bf16x8 kb1 = *(const bf16x8*)&Kb[kr1c * 72 + h * 32 + quad * 8];
                    f32x4 s0 = __builtin_amdgcn_mfma_f32_16x16x32_bf16(qa, kb0, Z, 0, 0, 0);
                    f32x4 s1 = __builtin_amdgcn_mfma_f32_16x16x32_bf16(qa, kb1, Z, 0, 0, 0);
                    __builtin_amdgcn_wave_barrier();
#pragma unroll
                    for (int rg = 0; rg < 4; ++rg) {
                        int rglob = q0 + quad * 4 + rg;
                        float e0 = (kr0 <= rglob && kr0 < SS) ? __expf(s0[rg] * scale) : 0.f;
                        float e1 = (kr1 <= rglob && kr1 < SS) ? __expf(s1[rg] * scale) : 0.f;
                        lsum[rg] += e0 + e1;
                        int prow = quad * 4 + rg;
                        ps[prow * 72 + m16] = f2b(e0);
                        ps[prow * 72 + 16 + m16] = f2b(e1);
                    }
                    __builtin_amdgcn_wave_barrier();
                    bf16x8 pa = *(const bf16x8*)&ps[m16 * 72 + quad * 8];
                    bf16x8 vb0 = *(const bf16x8*)&Vt[(h * 32 + m16) * 232 + p0 + quad * 8];
                    bf16x8 vb1 = *(const bf16x8*)&Vt[(h * 32 + 16 + m16) * 232 + p0 + quad * 8];
                    o0 = __builtin_amdgcn_mfma_f32_16x16x32_bf16(pa, vb0, o0, 0, 0, 0);
                    o1 = __builtin_amdgcn_mfma_f32_16x16x32_bf16(pa, vb1, o1, 0, 0, 0);
                }
#pragma unroll
                for (int rg = 0; rg < 4; ++rg)
#pragma unroll
                    for (int o = 1; o <= 8; o <<= 1) lsum[rg] += __shfl_xor(lsum[rg], o, 64);
                __builtin_amdgcn_wave_barrier();
#pragma unroll
                for (int rg = 0; rg < 4; ++rg) {
                    int rglob = q0 + quad * 4 + rg;
                    if (rglob < SS) {
                        float inv = 1.f / lsum[rg];
                        Qb[rglob * 72 + h * 32 + m16] = f2b(o0[rg] * inv);        // ctx in-place
                        Qb[rglob * 72 + h * 32 + 16 + m16] = f2b(o1[rg] * inv);
                    }
                }
            }
        }
        __syncthreads();
        // ---- FFN phase: entirely wave-local (own 16-row tile); zero block barriers ----
        if (w < 13) {
            int tb = w * 16;
            int row = tb + m16; if (row > 199) row = 199;
            // pass1: x1 = ctx*Wo + bo + LN0(x) -> Xf (raw); stats1; ln1 -> Kb
            {
                bf16x8 a0 = *(const bf16x8*)&Qb[row * 72 + quad * 8];
                bf16x8 a1 = *(const bf16x8*)&Qb[row * 72 + 32 + quad * 8];
#pragma unroll
                for (int nt = 0; nt < 4; ++nt) {
                    f32x4 acc = gemm1(a0, a1, wb + 24576 + l * 4096, nt, m16, quad);
                    int n = nt * 16 + m16;
                    float bbv = vecs[5][n], lw = vecs[3][n], lb = vecs[4][n];
#pragma unroll
                    for (int rg = 0; rg < 4; ++rg) {
                        int m = tb + quad * 4 + rg; int mc = m > 199 ? 199 : m;
                        float qin = (Xf[mc * XS + n] - stats[mc * 2]) * stats[mc * 2 + 1] * lw + lb;
                        float x1v = acc[rg] + bbv + qin;
                        if (m < 200) Xf[m * XS + n] = x1v;
                    }
                }
                __builtin_amdgcn_wave_barrier();
#pragma unroll
                for (int rg = 0; rg < 4; ++rg) {
                    int m = tb + quad * 4 + rg; int mc = m > 199 ? 199 : m;
                    float v0 = Xf[mc * XS + 0 + m16];
                    float v1 = Xf[mc * XS + 16 + m16];
                    float v2 = Xf[mc * XS + 32 + m16];
                    float v3 = Xf[mc * XS + 48 + m16];
                    float s1 = (v0 + v1) + (v2 + v3);
                    float s2 = v0 * v0 + v1 * v1 + v2 * v2 + v3 * v3;
#pragma unroll
                    for (int o = 1; o <= 8; o <<= 1) { s1 += __shfl_xor(s1, o, 64); s2 += __shfl_xor(s2, o, 64); }
                    float mean = s1 * (1.f / 64.f);
                    float var = s2 * (1.f / 64.f) - mean * mean;
                    float rs = rsqrtf(var + EPS);
                    if (m < 200 && m16 == 0) { stats[m * 2] = mean; stats[m * 2 + 1] = rs; }
#pragma unroll
                    for (int nt = 0; nt < 4; ++nt) {
                        int n = nt * 16 + m16;
                        float core = (Xf[mc * XS + n] - mean) * rs;
                        Kb[m * 72 + n] = f2b(core * vecs[8][n] + vecs[9][n]);
                    }
                }
            }
            __builtin_amdgcn_wave_barrier();
            // pass2: h = relu(ln1 * W1 + b1) -> Kb (own rows)
            {
                bf16x8 a0 = *(const bf16x8*)&Kb[(tb + m16) * 72 + quad * 8];
                bf16x8 a1 = *(const bf16x8*)&Kb[(tb + m16) * 72 + 32 + quad * 8];
                __builtin_amdgcn_wave_barrier();
#pragma unroll
                for (int nt = 0; nt < 4; ++nt) {
                    f32x4 acc = gemm1(a0, a1, wb + 32768 + l * 4096, nt, m16, quad);
                    int n = nt * 16 + m16; float bbv = vecs[6][n];
#pragma unroll
                    for (int rg = 0; rg < 4; ++rg)
                        Kb[(tb + quad * 4 + rg) * 72 + n] = f2b(fmaxf(acc[rg] + bbv, 0.f));
                }
            }
            __builtin_amdgcn_wave_barrier();
            // pass3: x = h*W2 + b2 + LN2(x1) -> Xf; stats for next layer
            {
                bf16x8 a0 = *(const bf16x8*)&Kb[(tb + m16) * 72 + quad * 8];
                bf16x8 a1 = *(const bf16x8*)&Kb[(tb + m16) * 72 + 32 + quad * 8];
#pragma unroll
                for (int nt = 0; nt < 4; ++nt) {
                    f32x4 acc = gemm1(a0, a1, wb + 40960 + l * 4096, nt, m16, quad);
                    int n = nt * 16 + m16;
                    float bbv = vecs[7][n], lw = vecs[10][n], lb = vecs[11][n];
#pragma unroll
                    for (int rg = 0; rg < 4; ++rg) {
                        int m = tb + quad * 4 + rg; int mc = m > 199 ? 199 : m;
                        float x1v = Xf[mc * XS + n];
                        float ln2 = (x1v - stats[mc * 2]) * stats[mc * 2 + 1] * lw + lb;
                        float xnv = acc[rg] + bbv + ln2;
                        if (m < 200) Xf[m * XS + n] = xnv;
                    }
                }
                __builtin_amdgcn_wave_barrier();
#pragma unroll
                for (int rg = 0; rg < 4; ++rg) {
                    int m = tb + quad * 4 + rg; int mc = m > 199 ? 199 : m;
                    float v0 = Xf[mc * XS + 0 + m16];
                    float v1 = Xf[mc * XS + 16 + m16];
                    float v2 = Xf[mc * XS + 32 + m16];
                    float v3 = Xf[mc * XS + 48 + m16];
                    float s1 = (v0 + v1) + (v2 + v3);
                    float s2 = v0 * v0 + v1 * v1 + v2 * v2 + v3 * v3;
#pragma unroll
                    for (int o = 1; o <= 8; o <<= 1) { s1 += __shfl_xor(s1, o, 64); s2 += __shfl_xor(s2, o, 64); }
                    float mean = s1 * (1.f / 64.f);
                    float var = s2 * (1.f / 64.f) - mean * mean;
                    float rs = rsqrtf(var + EPS);
                    if (m < 200 && m16 == 0) { stats[m * 2] = mean; stats[m * 2 + 1] = rs; }
                }
            }
        }
    }
    __syncthreads();

    // ---- epilogue: bf16 x out (gram-FF input) ----
    for (int i = t; i < 3200; i += 1024) {
        int r = i >> 4, c4 = (i & 15) * 4;
        float4 f = *(const float4*)&Xf[r * XS + c4];
        ushort4 o; o.x = f2b(f.x); o.y = f2b(f.y); o.z = f2b(f.z); o.w = f2b(f.w);
        *(ushort4*)&xb[((long)b * SS + r) * DDIM + c4] = o;
    }
    // ---- right(): ps = sum_d x*item_emb[pos]*pred_w ----
    float local = 0.f;
    {
        int rr = t >> 2;
        if (rr < 200) {
            int pi = pos_seqs[b * SS + rr];
            int qd = (t & 3) * 16;
            float v = 0.f;
#pragma unroll
            for (int g = 0; g < 4; ++g) {
                float4 xv = *(const float4*)&Xf[rr * XS + qd + g * 4];
                float4 iv = *(const float4*)&item_emb[(long)pi * DDIM + qd + g * 4];
                const float* pwp = &vecs[12][qd + g * 4];
                v += xv.x * iv.x * pwp[0] + xv.y * iv.y * pwp[1]
                   + xv.z * iv.z * pwp[2] + xv.w * iv.w * pwp[3];
            }
            v += __shfl_xor(v, 1, 64); v += __shfl_xor(v, 2, 64);
            if ((t & 3) == 0) local += (1.0f - CC) * v * v - 2.0f * v;
        }
    }
    local = wave_sum(local);
    if (lane == 0) redw[w] = local;
    __syncthreads();
    if (t == 0) {
        float s = 0.f;
#pragma unroll
        for (int i = 0; i < 16; ++i) s += redw[i];
        rpart[b] = s;
    }
}

// ---------------- MFMA Gram (combined EE f32 + FF bf16) ----------------
__global__ __launch_bounds__(256) void gram_kernel(const float* __restrict__ A0, int n0,
                                                   const unsigned short* __restrict__ A1, int n1,
                                                   float* __restrict__ part) {
    __shared__ unsigned short At[64 * LSTRIDE];   // At[c][r]
    int t = threadIdx.x;
    int second = blockIdx.x >= GRAM_NB;
    int bid = second ? blockIdx.x - GRAM_NB : blockIdx.x;
    int nrows = second ? n1 : n0;
    int w16 = (t >> 6) * 16, lane = t & 63, m16 = lane & 15, quad = lane >> 4;
    int bi = t & 15, bj = t >> 4;   // bi: col-block of A, bj: row-block
    f32x4 zero = {0.f, 0.f, 0.f, 0.f};
    f32x4 acc[4] = {zero, zero, zero, zero};
    for (long base = (long)bid * 64; base < nrows; base += (long)GRAM_NB * 64) {
        __syncthreads();   // protect At reads from previous iteration
        if (!second) {
            float rv[4][4];
#pragma unroll
            for (int e = 0; e < 4; ++e) {
                long gr = base + bj * 4 + e;
                float4 f = make_float4(0.f, 0.f, 0.f, 0.f);
                if (gr < nrows) f = *(const float4*)&A0[gr * DDIM + bi * 4];
                rv[e][0] = f.x; rv[e][1] = f.y; rv[e][2] = f.z; rv[e][3] = f.w;
            }
#pragma unroll
            for (int e = 0; e < 4; ++e) {
                ushort4 o;
                o.x = f2b(rv[0][e]); o.y = f2b(rv[1][e]); o.z = f2b(rv[2][e]); o.w = f2b(rv[3][e]);
                *(ushort4*)&At[(bi * 4 + e) * LSTRIDE + bj * 4] = o;
            }
        } else {
            ushort4 u[4];
#pragma unroll
            for (int e = 0; e < 4; ++e) {
                long gr = base + bj * 4 + e;
                ushort4 uu; uu.x = uu.y = uu.z = uu.w = 0;
                if (gr < nrows) uu = *(const ushort4*)&A1[gr * DDIM + bi * 4];
                u[e] = uu;
            }
#pragma unroll
            for (int e = 0; e < 4; ++e) {
                ushort4 o;
                o.x = ((const unsigned short*)&u[0])[e];
                o.y = ((const unsigned short*)&u[1])[e];
                o.z = ((const unsigned short*)&u[2])[e];
                o.w = ((const unsigned short*)&u[3])[e];
                *(ushort4*)&At[(bi * 4 + e) * LSTRIDE + bj * 4] = o;
            }
        }
        __syncthreads();
#pragma unroll
        for (int ks = 0; ks < 2; ++ks) {
            bf16x8 a = *(const bf16x8*)&At[(w16 + m16) * LSTRIDE + ks * 32 + quad * 8];
#pragma unroll
            for (int nt = 0; nt < 4; ++nt) {
                bf16x8 bfr = *(const bf16x8*)&At[(nt * 16 + m16) * LSTRIDE + ks * 32 + quad * 8];
                acc[nt] = __builtin_amdgcn_mfma_f32_16x16x32_bf16(a, bfr, acc[nt], 0, 0, 0);
            }
        }
    }
    float* slab = part + (long)blockIdx.x * 4096;
#pragma unroll
    for (int nt = 0; nt < 4; ++nt) {
        int n = nt * 16 + m16;
#pragma unroll
        for (int rg = 0; rg < 4; ++rg) {
            int m = w16 + quad * 4 + rg;
            slab[m * 64 + n] = acc[nt][rg];
        }
    }
}

// ---------------- per-parameter sum-of-squares ----------------
struct NormEntry { const float* p; int n; };
struct NormArgs { NormEntry e[30]; };

// blocks 0..31: gram reduce (0..15 EE, 16..31 FF); 32..61: norms; last finisher: final scalar
__global__ __launch_bounds__(256) void reduce_final(const float* __restrict__ part,
                                                    float* __restrict__ EE, float* __restrict__ FF,
                                                    NormArgs args, float* __restrict__ norms,
                                                    const float* __restrict__ pred_w,
                                                    const float* __restrict__ rpart,
                                                    unsigned int* __restrict__ cnt,
                                                    float* __restrict__ out) {
    __shared__ float red[256];
    __shared__ float redT[256];
    __shared__ float redR[256];
    __shared__ float p_s[64];
    __shared__ unsigned int amlast;
    int blk = blockIdx.x, t = threadIdx.x;
    if (blk < 32) {
        int which = blk >> 4;
        int p = (blk & 15) * 256 + t;
        const float* basep = part + (long)which * GRAM_NB * 4096;
        float s = 0.f;
        for (int b = 0; b < GRAM_NB; ++b) s += basep[(long)b * 4096 + p];
        (which ? FF : EE)[p] = s;
    } else {
        NormEntry en = args.e[blk - 32];
        float s = 0.f;
        for (int i = t; i < en.n; i += 256) { float v = en.p[i]; s += v * v; }
        red[t] = s;
        for (int o = 128; o > 0; o >>= 1) {
            __syncthreads();
            if (t < o) red[t] += red[t + o];
        }
        __syncthreads();
        if (t == 0) norms[blk - 32] = red[0];
    }
    // release: make this block's global writes visible, then count in
    __threadfence();
    __syncthreads();
    if (t == 0) amlast = atomicAdd(cnt, 1u);
    __syncthreads();
    if (amlast != 61) return;
    __threadfence();   // acquire: all 61 other blocks' writes now visible
    if (t < 64) p_s[t] = pred_w[t];
    __syncthreads();
    float lf = 0.f, tr = 0.f, rs = 0.f;
    for (int p = t; p < 4096; p += 256) {
        int i = p >> 6, j = p & 63;
        float ee = EE[p];
        lf += FF[p] * ee * p_s[i] * p_s[j];
        if (i == j) tr += ee;
    }
    for (int i = t; i < 512; i += 256) rs += rpart[i];
    red[t] = lf; redT[t] = tr; redR[t] = rs;
    for (int o = 128; o > 0; o >>= 1) {
        __syncthreads();
        if (t < o) { red[t] += red[t + o]; redT[t] += redT[t + o]; redR[t] += redR[t + o]; }
    }
    __syncthreads();
    if (t == 0) {
        float reg = sqrtf(redT[0]);   // ||item_emb||_F = sqrt(trace(EE))
        for (int s = 0; s < 30; ++s) reg += sqrtf(norms[s]);
        out[0] = CC * red[0] + redR[0] + 0.1f * reg;
    }
}

// ---------------- host ----------------
struct DevPtrs { float* gpart; unsigned short *qb, *wb; };

static DevPtrs fetch_ptrs() {
    DevPtrs p;
    (void)hipGetSymbolAddress((void**)&p.gpart, HIP_SYMBOL(g_gpart));
    (void)hipGetSymbolAddress((void**)&p.qb,    HIP_SYMBOL(g_qb));
    (void)hipGetSymbolAddress((void**)&p.wb,    HIP_SYMBOL(g_wb));
    return p;
}

extern "C" void kernel_launch(void* const* d_in, const int* in_sizes, int n_in,
                              void* d_out, int out_size, void* d_ws, size_t ws_size,
                              hipStream_t stream) {
    const int*   log_seqs = (const int*)d_in[1];
    const int*   pos_seqs = (const int*)d_in[2];
    const float* item_emb = (const float*)d_in[3];
    const float* pos_emb  = (const float*)d_in[4];
    const float* pred_w   = (const float*)d_in[5];
    const float* ln_w     = (const float*)d_in[6];
    const float* ln_b     = (const float*)d_in[7];
    const float* qkv_w    = (const float*)d_in[8];
    const float* qkv_b    = (const float*)d_in[9];
    const float* out_w    = (const float*)d_in[10];
    const float* out_b    = (const float*)d_in[11];
    const float* fc1_w    = (const float*)d_in[12];
    const float* fc1_b    = (const float*)d_in[13];
    const float* ffln_w   = (const float*)d_in[14];
    const float* ffln_b   = (const float*)d_in[15];
    const float* fc2_w    = (const float*)d_in[16];
    const float* fc2_b    = (const float*)d_in[17];
    const float* ffln2_w  = (const float*)d_in[18];
    const float* ffln2_b  = (const float*)d_in[19];

    static DevPtrs P = fetch_ptrs();   // first call is the uncaptured correctness call

    float* ws    = (float*)d_ws;
    float* rpart = ws;                              // 512
    unsigned int* cnt = (unsigned int*)(ws + 1600); // 1 (zeroed by mega block 0)
    float* nrm   = ws + 1664;                       // 30
    float* EE    = ws + 2048;                       // 4096
    float* FF    = ws + 6144;                       // 4096

    // bf16 weight conversion (once per launch, ~2 us)
    prep_weights<<<48, 256, 0, stream>>>(qkv_w, out_w, fc1_w, fc2_w, P.wb);

    // whole transformer + right(), one block per batch element, 16 waves
    mega<<<BB, 1024, 0, stream>>>(log_seqs, pos_seqs, item_emb, pos_emb, pred_w,
                                  ln_w, ln_b, qkv_b, out_b, fc1_b, fc2_b,
                                  ffln_w, ffln_b, ffln2_w, ffln2_b,
                                  P.wb, P.qb, rpart, cnt);

    gram_kernel<<<2 * GRAM_NB, 256, 0, stream>>>(item_emb, 100001, P.qb, NROWS, P.gpart);

    NormArgs na;
    int s = 0;
    na.e[s++] = {pos_emb, (SS + 1) * DDIM};
    na.e[s++] = {pred_w, DDIM};
    for (int l = 0; l < LL; ++l) {
        na.e[s++] = {ln_w + l * 64, 64};
        na.e[s++] = {ln_b + l * 64, 64};
        na.e[s++] = {qkv_w + (long)l * 12288, 12288};
        na.e[s++] = {qkv_b + (long)l * 192, 192};
        na.e[s++] = {out_w + (long)l * 4096, 4096};
        na.e[s++] = {out_b + l * 64, 64};
        na.e[s++] = {fc1_w + (long)l * 4096, 4096};
        na.e[s++] = {fc1_b + l * 64, 64};
        na.e[s++] = {ffln_w + l * 64, 64};
        na.e[s++] = {ffln_b + l * 64, 64};
        na.e[s++] = {fc2_w + (long)l * 4096, 4096};
        na.e[s++] = {fc2_b + l * 64, 64};
        na.e[s++] = {ffln2_w + l * 64, 64};
        na.e[s++] = {ffln2_b + l * 64, 64};
    }
    reduce_final<<<62, 256, 0, stream>>>(P.gpart, EE, FF, na, nrm, pred_w, rpart, cnt,
                                         (float*)d_out);
}

// Round 12
// 239.302 us; speedup vs baseline: 1.1226x; 1.1226x over previous
//
#include <hip/hip_runtime.h>
#include <hip/hip_bf16.h>
#include <math.h>

#define BB 512
#define SS 200
#define DDIM 64
#define HD 32
#define LL 2
#define NROWS (BB * SS)   // 102400
#define EPS 1e-8f
#define CC 0.001f
#define GRAM_NB 256       // blocks PER INPUT; combined kernel launches 2*GRAM_NB
#define LSTRIDE 72
#define XS 68             // Xf f32 LDS stride
#define QROWS 208         // Qb/Kb rows (16-row tiles up to 207 for tile 12)

typedef __attribute__((ext_vector_type(8))) short bf16x8;
typedef __attribute__((ext_vector_type(4))) float f32x4;

// ---------------- static device buffers ----------------
__device__ unsigned short g_qb[NROWS * DDIM];   // final bf16 x (gram-FF input)
__device__ float g_gpart[2 * GRAM_NB * 4096];   // gram per-block partials (EE slabs then FF slabs)

// ---------------- helpers ----------------
__device__ __forceinline__ float wave_sum(float v) {
#pragma unroll
    for (int o = 32; o > 0; o >>= 1) v += __shfl_xor(v, o, 64);
    return v;
}
// RNE f32->bf16 via native cast (fuses to v_cvt_pk_bf16_f32 for adjacent pairs)
__device__ __forceinline__ unsigned short f2b(float f) {
    __hip_bfloat16 h = __float2bfloat16(f);
    unsigned short u; __builtin_memcpy(&u, &h, 2); return u;
}

// ---------------- fragment builders (from LDS f32 x + per-row LN stats) ----------------
__device__ __forceinline__ bf16x8 frag_raw(const float* Xf, int row, int c0) {
    const float* p = &Xf[row * XS + c0];
    float4 u = *(const float4*)p;
    float4 v = *(const float4*)(p + 4);
    bf16x8 r;
    r[0] = (short)f2b(u.x); r[1] = (short)f2b(u.y); r[2] = (short)f2b(u.z); r[3] = (short)f2b(u.w);
    r[4] = (short)f2b(v.x); r[5] = (short)f2b(v.y); r[6] = (short)f2b(v.z); r[7] = (short)f2b(v.w);
    return r;
}
__device__ __forceinline__ bf16x8 frag_ln(const float* Xf, const float* stats,
                                          const float* vw, const float* vb,
                                          int row, int c0) {
    float m = stats[row * 2], rs = stats[row * 2 + 1];
    const float* p = &Xf[row * XS + c0];
    float4 u = *(const float4*)p;
    float4 v = *(const float4*)(p + 4);
    bf16x8 r;
    r[0] = (short)f2b((u.x - m) * rs * vw[c0 + 0] + vb[c0 + 0]);
    r[1] = (short)f2b((u.y - m) * rs * vw[c0 + 1] + vb[c0 + 1]);
    r[2] = (short)f2b((u.z - m) * rs * vw[c0 + 2] + vb[c0 + 2]);
    r[3] = (short)f2b((u.w - m) * rs * vw[c0 + 3] + vb[c0 + 3]);
    r[4] = (short)f2b((v.x - m) * rs * vw[c0 + 4] + vb[c0 + 4]);
    r[5] = (short)f2b((v.y - m) * rs * vw[c0 + 5] + vb[c0 + 5]);
    r[6] = (short)f2b((v.z - m) * rs * vw[c0 + 6] + vb[c0 + 6]);
    r[7] = (short)f2b((v.w - m) * rs * vw[c0 + 7] + vb[c0 + 7]);
    return r;
}

// ---------------- mega kernel: one block per batch element, 16 waves ----------------
// r11 post-mortem: global-direct B reads stall per-nt -> revert to r10 LDS tile.
// New: (1) issue-early/write-late weight prefetch (wpre regs) hides all 12 stage
// loads under prior compute (W1 hides under attention); (2) native bf16 casts
// (RNE, bit-identical) fuse to v_cvt_pk_bf16_f32, cutting conversion VALU.
__global__ __launch_bounds__(1024)
void mega(const int* __restrict__ log_seqs,
          const int* __restrict__ pos_seqs,
          const float* __restrict__ item_emb,
          const float* __restrict__ pos_emb,
          const float* __restrict__ pred_w,
          const float* __restrict__ ln_w,  const float* __restrict__ ln_b,
          const float* __restrict__ qkv_b,
          const float* __restrict__ out_b,
          const float* __restrict__ fc1_b, const float* __restrict__ fc2_b,
          const float* __restrict__ ffln_w, const float* __restrict__ ffln_b,
          const float* __restrict__ ffln2_w, const float* __restrict__ ffln2_b,
          const float* __restrict__ qkv_w, const float* __restrict__ out_w,
          const float* __restrict__ fc1_w, const float* __restrict__ fc2_w,
          unsigned short* __restrict__ xb,
          float* __restrict__ rpart,
          unsigned int* __restrict__ cnt) {
    __shared__ float Xf[200 * XS];               // 54,400 B  f32 activations / x1 stash
    __shared__ unsigned short Qb[QROWS * 72];    // 29,952 B  q -> P scratch -> ctx
    __shared__ unsigned short Kb[QROWS * 72];    // 29,952 B  k -> FFN scratch
    __shared__ unsigned short Vt[64 * 232];      // 29,696 B  V transposed [d][kk], pad cols 200..231 zero
    __shared__ unsigned short Wb[64 * LSTRIDE];  // 9,216 B   staged weight tile
    __shared__ float stats[200 * 2];             // 1,600 B   per-row (mean, rs)
    __shared__ float vecs[13][64];               // 3,328 B
    __shared__ float redw[16];
    // total 158,208 B -> 1 block/CU, 16 waves

    const int t = threadIdx.x, b = blockIdx.x;
    const int w = t >> 6, lane = t & 63, m16 = lane & 15, quad = lane >> 4;
    const int wr = t >> 4, wc4 = (t & 15) * 4;   // weight-stage mapping
    const f32x4 Z = {0.f, 0.f, 0.f, 0.f};

#define PRE(ptr) wpre = *(const float4*)&(ptr)[wr * 64 + wc4]
#define COMMIT() do { ushort4 o_; o_.x = f2b(wpre.x); o_.y = f2b(wpre.y); \
                      o_.z = f2b(wpre.z); o_.w = f2b(wpre.w); \
                      *(ushort4*)&Wb[wr * LSTRIDE + wc4] = o_; } while (0)

    float4 wpre;
    PRE(qkv_w);                                  // prefetch Wq(l=0); hides under embed

    if (b == 0 && t == 0) *cnt = 0u;             // reset reduce_final's done-counter
    if (t < 64) vecs[12][t] = pred_w[t];
    // Vt zero-pad cols 200..231, once (V writes are guarded to cols <200)
    if (t < 512) {
        int r2 = t >> 3, cc = 200 + (t & 7) * 4;
        ushort4 z4; z4.x = z4.y = z4.z = z4.w = 0;
        *(ushort4*)&Vt[r2 * 232 + cc] = z4;
    }
    // ---- embed + layer-0 LN stats (4 lanes per row) ----
    {
        int rr = t >> 2;
        if (rr < 200) {
            int li = log_seqs[b * SS + rr];
            int poss = li ? (rr + 1) : 0;
            int qd = (t & 3) * 16;
            float4 v[4];
#pragma unroll
            for (int g = 0; g < 4; ++g) {
                float4 e = *(const float4*)&item_emb[(long)li * DDIM + qd + g * 4];
                float4 p = *(const float4*)&pos_emb[(long)poss * DDIM + qd + g * 4];
                v[g].x = e.x * 8.0f + p.x; v[g].y = e.y * 8.0f + p.y;
                v[g].z = e.z * 8.0f + p.z; v[g].w = e.w * 8.0f + p.w;
                *(float4*)&Xf[rr * XS + qd + g * 4] = v[g];
            }
            float s1 = 0.f, s2 = 0.f;
#pragma unroll
            for (int g = 0; g < 4; ++g) {
                s1 += (v[g].x + v[g].y) + (v[g].z + v[g].w);
                s2 += (v[g].x * v[g].x + v[g].y * v[g].y) + (v[g].z * v[g].z + v[g].w * v[g].w);
            }
            s1 += __shfl_xor(s1, 1, 64); s1 += __shfl_xor(s1, 2, 64);
            s2 += __shfl_xor(s2, 1, 64); s2 += __shfl_xor(s2, 2, 64);
            float mean = s1 * (1.f / 64.f);
            float var = s2 * (1.f / 64.f) - mean * mean;
            float rs = rsqrtf(var + EPS);
            if ((t & 3) == 0) { stats[rr * 2] = mean; stats[rr * 2 + 1] = rs; }
        }
    }

#pragma unroll
    for (int l = 0; l < LL; ++l) {
        __syncthreads();                 // prev compute (embed / FFN3) done; Wb free
        COMMIT();                        // Wq -> Wb
        PRE(qkv_w + l * 12288 + 4096);   // prefetch Wk
        if (t < 64) {
            vecs[0][t] = qkv_b[l * 192 + t];
            vecs[1][t] = qkv_b[l * 192 + 64 + t];
            vecs[2][t] = qkv_b[l * 192 + 128 + t];
            vecs[3][t] = ln_w[l * 64 + t];   vecs[4][t] = ln_b[l * 64 + t];
            vecs[5][t] = out_b[l * 64 + t];
            vecs[6][t] = fc1_b[l * 64 + t];  vecs[7][t] = fc2_b[l * 64 + t];
            vecs[8][t] = ffln_w[l * 64 + t]; vecs[9][t] = ffln_b[l * 64 + t];
            vecs[10][t] = ffln2_w[l * 64 + t]; vecs[11][t] = ffln2_b[l * 64 + t];
        }
        __syncthreads();
        // ---- Q sub-phase (A = LN(x)); one acc live per nt ----
        if (w < 13) {
            int tb = w * 16;
            int row = tb + m16; if (row > 199) row = 199;
            bf16x8 a0 = frag_ln(Xf, stats, vecs[3], vecs[4], row, quad * 8);
            bf16x8 a1 = frag_ln(Xf, stats, vecs[3], vecs[4], row, 32 + quad * 8);
#pragma unroll
            for (int nt = 0; nt < 4; ++nt) {
                bf16x8 b0 = *(const bf16x8*)&Wb[(nt * 16 + m16) * LSTRIDE + quad * 8];
                bf16x8 b1 = *(const bf16x8*)&Wb[(nt * 16 + m16) * LSTRIDE + 32 + quad * 8];
                f32x4 acc = Z;
                acc = __builtin_amdgcn_mfma_f32_16x16x32_bf16(a0, b0, acc, 0, 0, 0);
                acc = __builtin_amdgcn_mfma_f32_16x16x32_bf16(a1, b1, acc, 0, 0, 0);
                int n = nt * 16 + m16; float bbv = vecs[0][n];
#pragma unroll
                for (int rg = 0; rg < 4; ++rg)
                    Qb[(tb + quad * 4 + rg) * 72 + n] = f2b(acc[rg] + bbv);
            }
        }
        __syncthreads();
        COMMIT();                        // Wk -> Wb
        PRE(qkv_w + l * 12288 + 8192);   // prefetch Wv
        __syncthreads();
        // ---- K sub-phase (A = bf16(x)) ----
        if (w < 13) {
            int tb = w * 16;
            int row = tb + m16; if (row > 199) row = 199;
            bf16x8 a0 = frag_raw(Xf, row, quad * 8);
            bf16x8 a1 = frag_raw(Xf, row, 32 + quad * 8);
#pragma unroll
            for (int nt = 0; nt < 4; ++nt) {
                bf16x8 b0 = *(const bf16x8*)&Wb[(nt * 16 + m16) * LSTRIDE + quad * 8];
                bf16x8 b1 = *(const bf16x8*)&Wb[(nt * 16 + m16) * LSTRIDE + 32 + quad * 8];
                f32x4 acc = Z;
                acc = __builtin_amdgcn_mfma_f32_16x16x32_bf16(a0, b0, acc, 0, 0, 0);
                acc = __builtin_amdgcn_mfma_f32_16x16x32_bf16(a1, b1, acc, 0, 0, 0);
                int n = nt * 16 + m16; float bbv = vecs[1][n];
#pragma unroll
                for (int rg = 0; rg < 4; ++rg)
                    Kb[(tb + quad * 4 + rg) * 72 + n] = f2b(acc[rg] + bbv);
            }
        }
        __syncthreads();
        COMMIT();                        // Wv -> Wb
        PRE(out_w + l * 4096);           // prefetch Wo
        __syncthreads();
        // ---- V sub-phase (A = bf16(x)), write transposed ----
        if (w < 13) {
            int tb = w * 16;
            int row = tb + m16; if (row > 199) row = 199;
            bf16x8 a0 = frag_raw(Xf, row, quad * 8);
            bf16x8 a1 = frag_raw(Xf, row, 32 + quad * 8);
#pragma unroll
            for (int nt = 0; nt < 4; ++nt) {
                bf16x8 b0 = *(const bf16x8*)&Wb[(nt * 16 + m16) * LSTRIDE + quad * 8];
                bf16x8 b1 = *(const bf16x8*)&Wb[(nt * 16 + m16) * LSTRIDE + 32 + quad * 8];
                f32x4 acc = Z;
                acc = __builtin_amdgcn_mfma_f32_16x16x32_bf16(a0, b0, acc, 0, 0, 0);
                acc = __builtin_amdgcn_mfma_f32_16x16x32_bf16(a1, b1, acc, 0, 0, 0);
                int n = nt * 16 + m16; float bbv = vecs[2][n];
#pragma unroll
                for (int rg = 0; rg < 4; ++rg) {
                    int m = tb + quad * 4 + rg;
                    if (m < 200) Vt[n * 232 + m] = f2b(acc[rg] + bbv);   // keep pad zero
                }
            }
        }
        __syncthreads();
        COMMIT();                        // Wo -> Wb (attn doesn't use Wb)
        PRE(fc1_w + l * 4096);           // prefetch W1; load hides under attention
        // ---- attention: 26 (h,qt) units over waves 0..13, np<=7 each; P reuses own Q region ----
        {
            const unsigned long long tab0 = 0x01170016FF19FF18ull;
            const unsigned long long tab1 = 0x0513041203150214ull;
            const unsigned long long tab2 = 0x090F080E07110610ull;
            const unsigned long long tab3 = 0xFFFFFFFF0B0D0A0Cull;
            unsigned long long tv = (w & 8) ? ((w & 4) ? tab3 : tab2) : ((w & 4) ? tab1 : tab0);
            unsigned su = (unsigned)((tv >> ((w & 3) * 16)) & 0xFFFFu);
            const float scale = 0.17677669529663687f;   // 1/sqrt(32)
            for (int slot = 0; slot < 2; ++slot) {
                int u = (su >> (slot * 8)) & 0xFF;
                if (u == 0xFF) break;
                int h = u & 1, qt = u >> 1;
                int q0 = qt * 16;
                int qrow = q0 + m16; if (qrow > 199) qrow = 199;
                bf16x8 qa = *(const bf16x8*)&Qb[qrow * 72 + h * 32 + quad * 8];
                __builtin_amdgcn_wave_barrier();
                unsigned short* ps = &Qb[q0 * 72 + h * 32];   // this unit's (now dead) Q region
                f32x4 o0 = Z, o1 = Z;
                float lsum[4] = {0.f, 0.f, 0.f, 0.f};
                int np = (qt + 2) >> 1;
                for (int pi = 0; pi < np; ++pi) {
                    int p0 = pi * 32;
                    int kr0 = p0 + m16;      int kr0c = kr0 > 199 ? 199 : kr0;
                    int kr1 = p0 + 16 + m16; int kr1c = kr1 > 199 ? 199 : kr1;
                    bf16x8 kb0 = *(const bf16x8*)&Kb[kr0c * 72 + h * 32 + quad * 8];
                    bf16x8 kb1 = *(const bf16x8*)&Kb[kr1c * 72 + h * 32 + quad * 8];
                    f32x4 s0 = __builtin_amdgcn_mfma_f32_16x16x32_bf16(qa, kb0, Z, 0, 0, 0);
                    f32x4 s1 = __builtin_amdgcn_mfma_f32_16x16x32_bf16(qa, kb1, Z, 0, 0, 0);
                    __builtin_amdgcn_wave_barrier();
#pragma unroll
                    for (int rg = 0; rg < 4; ++rg) {
                        int rglob = q0 + quad * 4 + rg;
                        float e0 = (kr0 <= rglob && kr0 < SS) ? __expf(s0[rg] * scale) : 0.f;
                        float e1 = (kr1 <= rglob && kr1 < SS) ? __expf(s1[rg] * scale) : 0.f;
                        lsum[rg] += e0 + e1;
                        int prow = quad * 4 + rg;
                        ps[prow * 72 + m16] = f2b(e0);
                        ps[prow * 72 + 16 + m16] = f2b(e1);
                    }
                    __builtin_amdgcn_wave_barrier();
                    bf16x8 pa = *(const bf16x8*)&ps[m16 * 72 + quad * 8];
                    bf16x8 vb0 = *(const bf16x8*)&Vt[(h * 32 + m16) * 232 + p0 + quad * 8];
                    bf16x8 vb1 = *(const bf16x8*)&Vt[(h * 32 + 16 + m16) * 232 + p0 + quad * 8];
                    o0 = __builtin_amdgcn_mfma_f32_16x16x32_bf16(pa, vb0, o0, 0, 0, 0);
                    o1 = __builtin_amdgcn_mfma_f32_16x16x32_bf16(pa, vb1, o1, 0, 0, 0);
                }
#pragma unroll
                for (int rg = 0; rg < 4; ++rg)
#pragma unroll
                    for (int o = 1; o <= 8; o <<= 1) lsum[rg] += __shfl_xor(lsum[rg], o, 64);
                __builtin_amdgcn_wave_barrier();
#pragma unroll
                for (int rg = 0; rg < 4; ++rg) {
                    int rglob = q0 + quad * 4 + rg;
                    if (rglob < SS) {
                        float inv = 1.f / lsum[rg];
                        Qb[rglob * 72 + h * 32 + m16] = f2b(o0[rg] * inv);        // ctx in-place
                        Qb[rglob * 72 + h * 32 + 16 + m16] = f2b(o1[rg] * inv);
                    }
                }
            }
        }
        __syncthreads();
        // ---- FFN pass1: x1 = ctx*Wo + bo + LN0(x) -> Xf (raw); stats1; ln1 -> Kb ----
        if (w < 13) {
            int tb = w * 16;
            int row = tb + m16; if (row > 199) row = 199;
            bf16x8 a0 = *(const bf16x8*)&Qb[row * 72 + quad * 8];
            bf16x8 a1 = *(const bf16x8*)&Qb[row * 72 + 32 + quad * 8];
#pragma unroll
            for (int nt = 0; nt < 4; ++nt) {
                bf16x8 b0 = *(const bf16x8*)&Wb[(nt * 16 + m16) * LSTRIDE + quad * 8];
                bf16x8 b1 = *(const bf16x8*)&Wb[(nt * 16 + m16) * LSTRIDE + 32 + quad * 8];
                f32x4 acc = Z;
                acc = __builtin_amdgcn_mfma_f32_16x16x32_bf16(a0, b0, acc, 0, 0, 0);
                acc = __builtin_amdgcn_mfma_f32_16x16x32_bf16(a1, b1, acc, 0, 0, 0);
                int n = nt * 16 + m16;
                float bbv = vecs[5][n], lw = vecs[3][n], lb = vecs[4][n];
#pragma unroll
                for (int rg = 0; rg < 4; ++rg) {
                    int m = tb + quad * 4 + rg; int mc = m > 199 ? 199 : m;
                    float qin = (Xf[mc * XS + n] - stats[mc * 2]) * stats[mc * 2 + 1] * lw + lb;
                    float x1v = acc[rg] + bbv + qin;
                    if (m < 200) Xf[m * XS + n] = x1v;
                }
            }
            __builtin_amdgcn_wave_barrier();
            // x1 stats (read-back; bit-identical pairwise order) + ln1 -> Kb
#pragma unroll
            for (int rg = 0; rg < 4; ++rg) {
                int m = tb + quad * 4 + rg; int mc = m > 199 ? 199 : m;
                float v0 = Xf[mc * XS + 0 + m16];
                float v1 = Xf[mc * XS + 16 + m16];
                float v2 = Xf[mc * XS + 32 + m16];
                float v3 = Xf[mc * XS + 48 + m16];
                float s1 = (v0 + v1) + (v2 + v3);
                float s2 = v0 * v0 + v1 * v1 + v2 * v2 + v3 * v3;
#pragma unroll
                for (int o = 1; o <= 8; o <<= 1) { s1 += __shfl_xor(s1, o, 64); s2 += __shfl_xor(s2, o, 64); }
                float mean = s1 * (1.f / 64.f);
                float var = s2 * (1.f / 64.f) - mean * mean;
                float rs = rsqrtf(var + EPS);
                if (m < 200 && m16 == 0) { stats[m * 2] = mean; stats[m * 2 + 1] = rs; }
#pragma unroll
                for (int nt = 0; nt < 4; ++nt) {
                    int n = nt * 16 + m16;
                    float core = (Xf[mc * XS + n] - mean) * rs;
                    Kb[m * 72 + n] = f2b(core * vecs[8][n] + vecs[9][n]);
                }
            }
        }
        __syncthreads();
        COMMIT();                        // W1 -> Wb
        PRE(fc2_w + l * 4096);           // prefetch W2
        __syncthreads();
        // ---- FFN pass2: h = relu(ln1 * W1 + b1) -> Kb (own rows) ----
        if (w < 13) {
            int tb = w * 16;
            bf16x8 a0 = *(const bf16x8*)&Kb[(tb + m16) * 72 + quad * 8];
            bf16x8 a1 = *(const bf16x8*)&Kb[(tb + m16) * 72 + 32 + quad * 8];
            __builtin_amdgcn_wave_barrier();
#pragma unroll
            for (int nt = 0; nt < 4; ++nt) {
                bf16x8 b0 = *(const bf16x8*)&Wb[(nt * 16 + m16) * LSTRIDE + quad * 8];
                bf16x8 b1 = *(const bf16x8*)&Wb[(nt * 16 + m16) * LSTRIDE + 32 + quad * 8];
                f32x4 acc = Z;
                acc = __builtin_amdgcn_mfma_f32_16x16x32_bf16(a0, b0, acc, 0, 0, 0);
                acc = __builtin_amdgcn_mfma_f32_16x16x32_bf16(a1, b1, acc, 0, 0, 0);
                int n = nt * 16 + m16; float bbv = vecs[6][n];
#pragma unroll
                for (int rg = 0; rg < 4; ++rg)
                    Kb[(tb + quad * 4 + rg) * 72 + n] = f2b(fmaxf(acc[rg] + bbv, 0.f));
            }
        }
        __syncthreads();
        COMMIT();                        // W2 -> Wb
        PRE((l + 1 < LL) ? (qkv_w + (l + 1) * 12288) : qkv_w);   // next Wq (or dummy)
        __syncthreads();
        // ---- FFN pass3: x = h*W2 + b2 + LN2(x1) -> Xf; stats for next layer ----
        if (w < 13) {
            int tb = w * 16;
            bf16x8 a0 = *(const bf16x8*)&Kb[(tb + m16) * 72 + quad * 8];
            bf16x8 a1 = *(const bf16x8*)&Kb[(tb + m16) * 72 + 32 + quad * 8];
#pragma unroll
            for (int nt = 0; nt < 4; ++nt) {
                bf16x8 b0 = *(const bf16x8*)&Wb[(nt * 16 + m16) * LSTRIDE + quad * 8];
                bf16x8 b1 = *(const bf16x8*)&Wb[(nt * 16 + m16) * LSTRIDE + 32 + quad * 8];
                f32x4 acc = Z;
                acc = __builtin_amdgcn_mfma_f32_16x16x32_bf16(a0, b0, acc, 0, 0, 0);
                acc = __builtin_amdgcn_mfma_f32_16x16x32_bf16(a1, b1, acc, 0, 0, 0);
                int n = nt * 16 + m16;
                float bbv = vecs[7][n], lw = vecs[10][n], lb = vecs[11][n];
#pragma unroll
                for (int rg = 0; rg < 4; ++rg) {
                    int m = tb + quad * 4 + rg; int mc = m > 199 ? 199 : m;
                    float x1v = Xf[mc * XS + n];
                    float ln2 = (x1v - stats[mc * 2]) * stats[mc * 2 + 1] * lw + lb;
                    float xnv = acc[rg] + bbv + ln2;
                    if (m < 200) Xf[m * XS + n] = xnv;
                }
            }
            __builtin_amdgcn_wave_barrier();
            // x stats for next layer (read-back, pairwise order)
#pragma unroll
            for (int rg = 0; rg < 4; ++rg) {
                int m = tb + quad * 4 + rg; int mc = m > 199 ? 199 : m;
                float v0 = Xf[mc * XS + 0 + m16];
                float v1 = Xf[mc * XS + 16 + m16];
                float v2 = Xf[mc * XS + 32 + m16];
                float v3 = Xf[mc * XS + 48 + m16];
                float s1 = (v0 + v1) + (v2 + v3);
                float s2 = v0 * v0 + v1 * v1 + v2 * v2 + v3 * v3;
#pragma unroll
                for (int o = 1; o <= 8; o <<= 1) { s1 += __shfl_xor(s1, o, 64); s2 += __shfl_xor(s2, o, 64); }
                float mean = s1 * (1.f / 64.f);
                float var = s2 * (1.f / 64.f) - mean * mean;
                float rs = rsqrtf(var + EPS);
                if (m < 200 && m16 == 0) { stats[m * 2] = mean; stats[m * 2 + 1] = rs; }
            }
        }
    }
    __syncthreads();
#undef PRE
#undef COMMIT

    // ---- epilogue: bf16 x out (gram-FF input) ----
    for (int i = t; i < 3200; i += 1024) {
        int r = i >> 4, c4 = (i & 15) * 4;
        float4 f = *(const float4*)&Xf[r * XS + c4];
        ushort4 o; o.x = f2b(f.x); o.y = f2b(f.y); o.z = f2b(f.z); o.w = f2b(f.w);
        *(ushort4*)&xb[((long)b * SS + r) * DDIM + c4] = o;
    }
    // ---- right(): ps = sum_d x*item_emb[pos]*pred_w ----
    float local = 0.f;
    {
        int rr = t >> 2;
        if (rr < 200) {
            int pi = pos_seqs[b * SS + rr];
            int qd = (t & 3) * 16;
            float v = 0.f;
#pragma unroll
            for (int g = 0; g < 4; ++g) {
                float4 xv = *(const float4*)&Xf[rr * XS + qd + g * 4];
                float4 iv = *(const float4*)&item_emb[(long)pi * DDIM + qd + g * 4];
                const float* pwp = &vecs[12][qd + g * 4];
                v += xv.x * iv.x * pwp[0] + xv.y * iv.y * pwp[1]
                   + xv.z * iv.z * pwp[2] + xv.w * iv.w * pwp[3];
            }
            v += __shfl_xor(v, 1, 64); v += __shfl_xor(v, 2, 64);
            if ((t & 3) == 0) local += (1.0f - CC) * v * v - 2.0f * v;
        }
    }
    local = wave_sum(local);
    if (lane == 0) redw[w] = local;
    __syncthreads();
    if (t == 0) {
        float s = 0.f;
#pragma unroll
        for (int i = 0; i < 16; ++i) s += redw[i];
        rpart[b] = s;
    }
}

// ---------------- MFMA Gram (combined EE f32 + FF bf16) ----------------
__global__ __launch_bounds__(256) void gram_kernel(const float* __restrict__ A0, int n0,
                                                   const unsigned short* __restrict__ A1, int n1,
                                                   float* __restrict__ part) {
    __shared__ unsigned short At[64 * LSTRIDE];   // At[c][r]
    int t = threadIdx.x;
    int second = blockIdx.x >= GRAM_NB;
    int bid = second ? blockIdx.x - GRAM_NB : blockIdx.x;
    int nrows = second ? n1 : n0;
    int w16 = (t >> 6) * 16, lane = t & 63, m16 = lane & 15, quad = lane >> 4;
    int bi = t & 15, bj = t >> 4;   // bi: col-block of A, bj: row-block
    f32x4 zero = {0.f, 0.f, 0.f, 0.f};
    f32x4 acc[4] = {zero, zero, zero, zero};
    for (long base = (long)bid * 64; base < nrows; base += (long)GRAM_NB * 64) {
        __syncthreads();   // protect At reads from previous iteration
        if (!second) {
            float rv[4][4];
#pragma unroll
            for (int e = 0; e < 4; ++e) {
                long gr = base + bj * 4 + e;
                float4 f = make_float4(0.f, 0.f, 0.f, 0.f);
                if (gr < nrows) f = *(const float4*)&A0[gr * DDIM + bi * 4];
                rv[e][0] = f.x; rv[e][1] = f.y; rv[e][2] = f.z; rv[e][3] = f.w;
            }
#pragma unroll
            for (int e = 0; e < 4; ++e) {
                ushort4 o;
                o.x = f2b(rv[0][e]); o.y = f2b(rv[1][e]); o.z = f2b(rv[2][e]); o.w = f2b(rv[3][e]);
                *(ushort4*)&At[(bi * 4 + e) * LSTRIDE + bj * 4] = o;
            }
        } else {
            ushort4 u[4];
#pragma unroll
            for (int e = 0; e < 4; ++e) {
                long gr = base + bj * 4 + e;
                ushort4 uu; uu.x = uu.y = uu.z = uu.w = 0;
                if (gr < nrows) uu = *(const ushort4*)&A1[gr * DDIM + bi * 4];
                u[e] = uu;
            }
#pragma unroll
            for (int e = 0; e < 4; ++e) {
                ushort4 o;
                o.x = ((const unsigned short*)&u[0])[e];
                o.y = ((const unsigned short*)&u[1])[e];
                o.z = ((const unsigned short*)&u[2])[e];
                o.w = ((const unsigned short*)&u[3])[e];
                *(ushort4*)&At[(bi * 4 + e) * LSTRIDE + bj * 4] = o;
            }
        }
        __syncthreads();
#pragma unroll
        for (int ks = 0; ks < 2; ++ks) {
            bf16x8 a = *(const bf16x8*)&At[(w16 + m16) * LSTRIDE + ks * 32 + quad * 8];
#pragma unroll
            for (int nt = 0; nt < 4; ++nt) {
                bf16x8 bfr = *(const bf16x8*)&At[(nt * 16 + m16) * LSTRIDE + ks * 32 + quad * 8];
                acc[nt] = __builtin_amdgcn_mfma_f32_16x16x32_bf16(a, bfr, acc[nt], 0, 0, 0);
            }
        }
    }
    float* slab = part + (long)blockIdx.x * 4096;
#pragma unroll
    for (int nt = 0; nt < 4; ++nt) {
        int n = nt * 16 + m16;
#pragma unroll
        for (int rg = 0; rg < 4; ++rg) {
            int m = w16 + quad * 4 + rg;
            slab[m * 64 + n] = acc[nt][rg];
        }
    }
}

// ---------------- per-parameter sum-of-squares ----------------
struct NormEntry { const float* p; int n; };
struct NormArgs { NormEntry e[30]; };

// blocks 0..31: gram reduce (0..15 EE, 16..31 FF); 32..61: norms; last finisher: final scalar
__global__ __launch_bounds__(256) void reduce_final(const float* __restrict__ part,
                                                    float* __restrict__ EE, float* __restrict__ FF,
                                                    NormArgs args, float* __restrict__ norms,
                                                    const float* __restrict__ pred_w,
                                                    const float* __restrict__ rpart,
                                                    unsigned int* __restrict__ cnt,
                                                    float* __restrict__ out) {
    __shared__ float red[256];
    __shared__ float redT[256];
    __shared__ float redR[256];
    __shared__ float p_s[64];
    __shared__ unsigned int amlast;
    int blk = blockIdx.x, t = threadIdx.x;
    if (blk < 32) {
        int which = blk >> 4;
        int p = (blk & 15) * 256 + t;
        const float* basep = part + (long)which * GRAM_NB * 4096;
        float s = 0.f;
        for (int b = 0; b < GRAM_NB; ++b) s += basep[(long)b * 4096 + p];
        (which ? FF : EE)[p] = s;
    } else {
        NormEntry en = args.e[blk - 32];
        float s = 0.f;
        for (int i = t; i < en.n; i += 256) { float v = en.p[i]; s += v * v; }
        red[t] = s;
        for (int o = 128; o > 0; o >>= 1) {
            __syncthreads();
            if (t < o) red[t] += red[t + o];
        }
        __syncthreads();
        if (t == 0) norms[blk - 32] = red[0];
    }
    // release: make this block's global writes visible, then count in
    __threadfence();
    __syncthreads();
    if (t == 0) amlast = atomicAdd(cnt, 1u);
    __syncthreads();
    if (amlast != 61) return;
    __threadfence();   // acquire: all 61 other blocks' writes now visible
    if (t < 64) p_s[t] = pred_w[t];
    __syncthreads();
    float lf = 0.f, tr = 0.f, rs = 0.f;
    for (int p = t; p < 4096; p += 256) {
        int i = p >> 6, j = p & 63;
        float ee = EE[p];
        lf += FF[p] * ee * p_s[i] * p_s[j];
        if (i == j) tr += ee;
    }
    for (int i = t; i < 512; i += 256) rs += rpart[i];
    red[t] = lf; redT[t] = tr; redR[t] = rs;
    for (int o = 128; o > 0; o >>= 1) {
        __syncthreads();
        if (t < o) { red[t] += red[t + o]; redT[t] += redT[t + o]; redR[t] += redR[t + o]; }
    }
    __syncthreads();
    if (t == 0) {
        float reg = sqrtf(redT[0]);   // ||item_emb||_F = sqrt(trace(EE))
        for (int s = 0; s < 30; ++s) reg += sqrtf(norms[s]);
        out[0] = CC * red[0] + redR[0] + 0.1f * reg;
    }
}

// ---------------- host ----------------
struct DevPtrs { float* gpart; unsigned short* qb; };

static DevPtrs fetch_ptrs() {
    DevPtrs p;
    (void)hipGetSymbolAddress((void**)&p.gpart, HIP_SYMBOL(g_gpart));
    (void)hipGetSymbolAddress((void**)&p.qb,    HIP_SYMBOL(g_qb));
    return p;
}

extern "C" void kernel_launch(void* const* d_in, const int* in_sizes, int n_in,
                              void* d_out, int out_size, void* d_ws, size_t ws_size,
                              hipStream_t stream) {
    const int*   log_seqs = (const int*)d_in[1];
    const int*   pos_seqs = (const int*)d_in[2];
    const float* item_emb = (const float*)d_in[3];
    const float* pos_emb  = (const float*)d_in[4];
    const float* pred_w   = (const float*)d_in[5];
    const float* ln_w     = (const float*)d_in[6];
    const float* ln_b     = (const float*)d_in[7];
    const float* qkv_w    = (const float*)d_in[8];
    const float* qkv_b    = (const float*)d_in[9];
    const float* out_w    = (const float*)d_in[10];
    const float* out_b    = (const float*)d_in[11];
    const float* fc1_w    = (const float*)d_in[12];
    const float* fc1_b    = (const float*)d_in[13];
    const float* ffln_w   = (const float*)d_in[14];
    const float* ffln_b   = (const float*)d_in[15];
    const float* fc2_w    = (const float*)d_in[16];
    const float* fc2_b    = (const float*)d_in[17];
    const float* ffln2_w  = (const float*)d_in[18];
    const float* ffln2_b  = (const float*)d_in[19];

    static DevPtrs P = fetch_ptrs();   // first call is the uncaptured correctness call

    float* ws    = (float*)d_ws;
    float* rpart = ws;                              // 512
    unsigned int* cnt = (unsigned int*)(ws + 1600); // 1 (zeroed by mega block 0)
    float* nrm   = ws + 1664;                       // 30
    float* EE    = ws + 2048;                       // 4096
    float* FF    = ws + 6144;                       // 4096

    // whole transformer + right(), one block per batch element, 16 waves
    mega<<<BB, 1024, 0, stream>>>(log_seqs, pos_seqs, item_emb, pos_emb, pred_w,
                                  ln_w, ln_b, qkv_b, out_b, fc1_b, fc2_b,
                                  ffln_w, ffln_b, ffln2_w, ffln2_b,
                                  qkv_w, out_w, fc1_w, fc2_w,
                                  P.qb, rpart, cnt);

    gram_kernel<<<2 * GRAM_NB, 256, 0, stream>>>(item_emb, 100001, P.qb, NROWS, P.gpart);

    NormArgs na;
    int s = 0;
    na.e[s++] = {pos_emb, (SS + 1) * DDIM};
    na.e[s++] = {pred_w, DDIM};
    for (int l = 0; l < LL; ++l) {
        na.e[s++] = {ln_w + l * 64, 64};
        na.e[s++] = {ln_b + l * 64, 64};
        na.e[s++] = {qkv_w + (long)l * 12288, 12288};
        na.e[s++] = {qkv_b + (long)l * 192, 192};
        na.e[s++] = {out_w + (long)l * 4096, 4096};
        na.e[s++] = {out_b + l * 64, 64};
        na.e[s++] = {fc1_w + (long)l * 4096, 4096};
        na.e[s++] = {fc1_b + l * 64, 64};
        na.e[s++] = {ffln_w + l * 64, 64};
        na.e[s++] = {ffln_b + l * 64, 64};
        na.e[s++] = {fc2_w + (long)l * 4096, 4096};
        na.e[s++] = {fc2_b + l * 64, 64};
        na.e[s++] = {ffln2_w + l * 64, 64};
        na.e[s++] = {ffln2_b + l * 64, 64};
    }
    reduce_final<<<62, 256, 0, stream>>>(P.gpart, EE, FF, na, nrm, pred_w, rpart, cnt,
                                         (float*)d_out);
}